// Round 12
// baseline (771.396 us; speedup 1.0000x reference)
//
#include <hip/hip_runtime.h>

// LGA3: 3 chained local-guided-aggregation passes, rolling-accumulator stencil.
// R9 shell (cost tile via global_load_lds, weights batch-loaded to registers,
// padding via register masks, write-once LDS) + T3/T4-lite pipeline:
//   - cost LDS is a 3-deep ring: row r+2 staged during iter r
//   - raw s_barrier with COUNTED s_waitcnt vmcnt(N) at top of each iter
//     (next-row loads + stores stay in flight across the barrier; never 0)
//   - every wave issues exactly 3 gld_lds per stage (dummy chunks -> slack LDS)
//     and stages run every iter with clamped h, so vmcnt counts are constant.
// cost [B=2, D=64, H=384, W=768] fp32, weights [B, 75, H, W] fp32.
// out[b,d,h,w] = sum_{i,j in 5x5} w0*c[d-1,h+i-2,w+j-2] + w1*c[d,..] + w2*c[d+1,..]

#define B_ 2
#define D_ 64
#define H_ 384
#define W_ 768
static constexpr int HW    = H_ * W_;
static constexpr int DPT   = 8;          // disparities per thread
static constexpr int NTY   = D_ / DPT;   // 8 waves
static constexpr int WT    = 64;
static constexpr int HSEG  = 8;          // output rows per block
static constexpr int RITER = HSEG + 4;   // 12 streamed input rows
static constexpr int LROW  = 72;         // floats per LDS plane row (288 B)
static constexpr int NCH_C = 18;         // real 1 KiB chunks per cost-row stage
static constexpr int LBUF  = LROW + 19 * 256;  // rows 1..64 at LROW + c*256, +slack chunk 18

__device__ __forceinline__ void gld_lds16(const float* g, float* l) {
  __builtin_amdgcn_global_load_lds((const __attribute__((address_space(1))) unsigned int*)g,
                                   (__attribute__((address_space(3))) unsigned int*)l,
                                   16, 0, 0);
}

__global__ __launch_bounds__(512, 1) void lga_pass(const float* __restrict__ src,
                                                   const float* __restrict__ wts,
                                                   float* __restrict__ dst) {
  __shared__ float cl[3][LBUF];           // ~59 KB ring; write-once per buffer per pass

  const int tx = threadIdx.x;             // 0..63 (lane; wave = ty)
  const int ty = threadIdx.y;             // 0..7
  const int w0 = blockIdx.x * WT, w = w0 + tx;
  const int hs = blockIdx.y * HSEG;
  const int b  = blockIdx.z;
  const int d0 = ty * DPT;

  const float* sb  = src + (size_t)b * D_ * HW;
  const float* wtb = wts + (size_t)b * 75 * HW;

  const bool has_lo = (d0 > 0);
  const bool has_hi = (d0 + DPT < D_);
  bool wok[5];
#pragma unroll
  for (int j = 0; j < 5; ++j) wok[j] = (unsigned)(w + j - 2) < (unsigned)W_;

  // stage one input row into `buf` (rows 1..64). EVERY wave issues EXACTLY 3
  // gld_lds (chunks >=18 go to the slack region) so per-wave vmcnt is uniform.
  // h is clamped by the caller; w/d handled by index clamps + register masks.
  auto stage_c = [&](float* buf, int h_in) {
#pragma unroll
    for (int q = 0; q < 3; ++q) {
      const int c    = ty + q * 8;                 // 0..23, wave-uniform
      const bool real = (c < NCH_C);
      const int cc   = real ? c : NCH_C;           // slack chunk for dummies
      const int cg   = real ? c : 0;
      const int G    = cg * 64 + tx;
      const int d    = G / NCH_C;
      const int k    = G - d * NCH_C;
      long idx = (long)d * HW + (long)h_in * W_ + (w0 - 4) + (k << 2);
      idx = idx < 0 ? 0 : idx;
      const long mx = (long)D_ * HW - 4;
      idx = idx > mx ? mx : idx;
      gld_lds16(sb + idx, &buf[LROW + cc * 256]);
    }
  };

  auto clampH = [](int h) { return h < 0 ? 0 : (h >= H_ ? H_ - 1 : h); };

  // prologue: stage rows for iters 0 and 1 (clamped h; garbage rows never used)
  stage_c(cl[0], clampH(hs - 2));
  stage_c(cl[1], clampH(hs - 1));

  float acc[5][DPT];
#pragma unroll
  for (int s = 0; s < 5; ++s)
#pragma unroll
    for (int k = 0; k < DPT; ++k) acc[s][k] = 0.f;

#pragma unroll 1
  for (int r = 0; r < RITER; ++r) {
    // ---- 1. counted wait: my stage-r loads (oldest 3) retired; next-row loads
    //         and last iter's stores stay in flight. Then cross-wave barrier.
    if (r <= 4) { asm volatile("s_waitcnt vmcnt(3)" ::: "memory"); }
    else        { asm volatile("s_waitcnt vmcnt(11)" ::: "memory"); }
    __builtin_amdgcn_s_barrier();
    asm volatile("" ::: "memory");

    // ---- 2. batch weight prefetch: all 75 loads (slot order, uniform row base)
    float W[75];
#pragma unroll
    for (int s = 0; s < 5; ++s) {
      if ((unsigned)(r - 4 + s) < (unsigned)HSEG) {       // wave-uniform
        const int o     = hs + r - 4 + s;
        const int ib    = (4 - s) * 5;
        const float* wr = wtb + (size_t)o * W_;
#pragma unroll
        for (int g = 0; g < 3; ++g)
#pragma unroll
          for (int j = 0; j < 5; ++j)
            W[s * 15 + g * 5 + j] = wr[(size_t)(ib + j + 25 * g) * HW + w];
      }
    }

    // ---- 3. stage row r+2 into ring slot (r+2)%3 (safe: all waves passed the
    //         barrier, so nobody still reads that slot; read again at iter r+2)
    stage_c(cl[(r + 2) % 3], clampH(hs - 2 + r + 2));

    // ---- 4. LDS -> vv (raw read + register masking), from ring slot r%3
    const int  h_in = hs - 2 + r;
    const bool hv   = (unsigned)h_in < (unsigned)H_;      // wave-uniform
    float vv[5][DPT + 2];
    if (hv) {
      const float* vbase = cl[r % 3] + d0 * LROW + tx + 2;
#pragma unroll
      for (int j = 0; j < 5; ++j)
#pragma unroll
        for (int m = 0; m < DPT + 2; ++m) {
          const float v = vbase[m * LROW + j];
          bool ok = wok[j];
          if (m == 0)       ok = ok && has_lo;
          if (m == DPT + 1) ok = ok && has_hi;
          vv[j][m] = ok ? v : 0.f;
        }
    }

    // ---- 5. per-slot FMAs (slot s -> output row hs+r-4+s, tap row 4-s)
#pragma unroll
    for (int s = 0; s < 5; ++s) {
      if (hv && (unsigned)(r - 4 + s) < (unsigned)HSEG) {
#pragma unroll
        for (int j = 0; j < 5; ++j)
#pragma unroll
          for (int k = 0; k < DPT; ++k)
            acc[s][k] = fmaf(W[s * 15 + j],      vv[j][k],
                        fmaf(W[s * 15 + 5 + j],  vv[j][k + 1],
                        fmaf(W[s * 15 + 10 + j], vv[j][k + 2], acc[s][k])));
      }
    }

    // ---- 6. slot 0 complete -> write output row hs+r-4
    if (r >= 4) {
      const int o = hs + r - 4;
#pragma unroll
      for (int k = 0; k < DPT; ++k) {
        float* dp = dst + (((size_t)b * D_ + d0 + k) * H_ + o) * W_;
        dp[w] = acc[0][k];
      }
    }

    // ---- 7. rotate accumulator slots (static indices)
#pragma unroll
    for (int s = 0; s < 4; ++s)
#pragma unroll
      for (int k = 0; k < DPT; ++k) acc[s][k] = acc[s + 1][k];
#pragma unroll
    for (int k = 0; k < DPT; ++k) acc[4][k] = 0.f;
  }
}

extern "C" void kernel_launch(void* const* d_in, const int* in_sizes, int n_in,
                              void* d_out, int out_size, void* d_ws, size_t ws_size,
                              hipStream_t stream) {
  const float* cost = (const float*)d_in[0];
  const float* wts  = (const float*)d_in[1];
  float* out = (float*)d_out;
  float* ws  = (float*)d_ws;

  dim3 grid(W_ / WT, H_ / HSEG, B_);   // 12 x 48 x 2 = 1152 blocks
  dim3 block(WT, NTY);                 // 64 x 8 = 512 threads

  lga_pass<<<grid, block, 0, stream>>>(cost, wts, out);
  lga_pass<<<grid, block, 0, stream>>>(out, wts, ws);
  lga_pass<<<grid, block, 0, stream>>>(ws, wts, out);
}

// Round 13
// 552.822 us; speedup vs baseline: 1.3954x; 1.3954x over previous
//
#include <hip/hip_runtime.h>

// LGA3: 3 chained local-guided-aggregation passes, rolling-accumulator stencil.
// d-split variant (R10 structure, NO register cap): each 256-thread block
// (64w x 4 d-waves, DPT=8) owns 32 of 64 disparities -> 2304 blocks, ~4
// resident/CU as INDEPENDENT 4-wave barrier groups (each SIMD hosts waves of
// 4 different blocks at uncorrelated phases -> latency cover without lockstep).
// Cost planes in double-buffered write-once LDS (global_load_lds, 34-plane
// tile); weights batch-loaded to registers (R9); padding via register masks
// on edge blocks / d-edge waves only.
// cost [B=2, D=64, H=384, W=768] fp32, weights [B, 75, H, W] fp32.
// out[b,d,h,w] = sum_{i,j in 5x5} w0*c[d-1,h+i-2,w+j-2] + w1*c[d,..] + w2*c[d+1,..]

#define B_ 2
#define D_ 64
#define H_ 384
#define W_ 768
static constexpr int HW    = H_ * W_;
static constexpr int DPT   = 8;          // disparities per thread
static constexpr int NTY   = 4;          // 4 waves/block -> 32 d per block
static constexpr int WT    = 64;
static constexpr int HSEG  = 8;          // output rows per block
static constexpr int RITER = HSEG + 4;   // 12 streamed input rows
static constexpr int LROW  = 72;         // floats per LDS plane row (288 B)
static constexpr int LRWS  = 34;         // LDS rows: planes dbase..dbase+33
static constexpr int NGRAN = LRWS * 18;  // 612 granules of 16 B per stage
static constexpr int NCH   = 10;         // 1-KiB chunks per stage
static constexpr int LBUF  = NCH * 256;  // 2560 floats per buffer (chunk 9 slack)

__device__ __forceinline__ void gld_lds16(const float* g, float* l) {
  __builtin_amdgcn_global_load_lds((const __attribute__((address_space(1))) unsigned int*)g,
                                   (__attribute__((address_space(3))) unsigned int*)l,
                                   16, 0, 0);
}

__global__ __launch_bounds__(256, 1) void lga_pass(const float* __restrict__ src,
                                                   const float* __restrict__ wts,
                                                   float* __restrict__ dst) {
  __shared__ float cl[2][LBUF];           // 20480 B; write-once per buffer

  const int tx    = threadIdx.x;          // 0..63 (lane; wave = ty)
  const int ty    = threadIdx.y;          // 0..3
  const int bx    = blockIdx.x;
  const int w0    = bx * WT, w = w0 + tx;
  const int hs    = blockIdx.y * HSEG;
  const int b     = blockIdx.z >> 1;
  const int dhalf = blockIdx.z & 1;
  const int dbase = dhalf * 32 - 1;       // plane held in LDS row 0
  const int d0    = dhalf * 32 + ty * DPT;

  const float* sb  = src + (size_t)b * D_ * HW;
  const float* wtb = wts + (size_t)b * 75 * HW;

  const bool has_lo = (d0 > 0);
  const bool has_hi = (d0 + DPT < D_);
  const bool edge   = (bx == 0) || (bx == W_ / WT - 1);

  // stage one input row: LDS rows 0..33 <- planes clamp(dbase+p, 0, 63)
  auto stage = [&](int buf, int h_in) {
#pragma unroll
    for (int q = 0; q < 3; ++q) {
      const int c = ty + q * 4;                     // wave-uniform chunk id
      if (c < NCH) {
        int G = c * 64 + tx;                        // granule id
        G = G > NGRAN - 1 ? NGRAN - 1 : G;          // clamp tail (slack area)
        const int p  = G / 18;                      // LDS row
        const int k  = G - p * 18;                  // granule within row
        int pd = dbase + p;                         // source plane
        pd = pd < 0 ? 0 : (pd > D_ - 1 ? D_ - 1 : pd);
        long idx = (long)pd * HW + (long)h_in * W_ + (w0 - 4) + (k << 2);
        idx = idx < 0 ? 0 : idx;
        const long mx = (long)D_ * HW - 4;
        idx = idx > mx ? mx : idx;
        gld_lds16(sb + idx, &cl[buf][c * 256]);
      }
    }
  };

  // prologue: stage input row hs-2 into buf 0
  {
    const int h0 = hs - 2;
    if (h0 >= 0) stage(0, h0);
  }
  __syncthreads();

  float acc[5][DPT];
#pragma unroll
  for (int s = 0; s < 5; ++s)
#pragma unroll
    for (int k = 0; k < DPT; ++k) acc[s][k] = 0.f;

  int n = 0;
#pragma unroll 1
  for (int r = 0; r < RITER; ++r) {
    // ---- 1. batch weight prefetch: all 75 loads, slot order (earliest use first)
    float W[75];
#pragma unroll
    for (int s = 0; s < 5; ++s) {
      if ((unsigned)(r - 4 + s) < (unsigned)HSEG) {       // wave-uniform
        const int o     = hs + r - 4 + s;
        const int ib    = (4 - s) * 5;
        const float* wr = wtb + (size_t)o * W_;           // uniform row base
#pragma unroll
        for (int g = 0; g < 3; ++g)
#pragma unroll
          for (int j = 0; j < 5; ++j)
            W[s * 15 + g * 5 + j] = wr[(size_t)(ib + j + 25 * g) * HW + w];
      }
    }

    // ---- 2. async stage of next input row into the other buffer
    if (r + 1 < RITER) {
      const int h_nx = hs - 2 + r + 1;
      if ((unsigned)h_nx < (unsigned)H_) stage(n ^ 1, h_nx);
    }

    // ---- 3. LDS -> vv; masks only where needed (edge blocks / d-edge waves)
    const int  h_in = hs - 2 + r;
    const bool hv   = (unsigned)h_in < (unsigned)H_;      // wave-uniform
    float vv[5][DPT + 2];
    if (hv) {
      const float* vbase = cl[n] + ty * DPT * LROW + tx + 2;
      if (!edge) {                                        // interior: no lane masks
#pragma unroll
        for (int j = 0; j < 5; ++j)
#pragma unroll
          for (int m = 0; m < DPT + 2; ++m)
            vv[j][m] = vbase[m * LROW + j];
        if (!has_lo) {                                    // uniform wave branch
#pragma unroll
          for (int j = 0; j < 5; ++j) vv[j][0] = 0.f;
        }
        if (!has_hi) {
#pragma unroll
          for (int j = 0; j < 5; ++j) vv[j][DPT + 1] = 0.f;
        }
      } else {
#pragma unroll
        for (int j = 0; j < 5; ++j) {
          const bool wokj = (unsigned)(w + j - 2) < (unsigned)W_;
#pragma unroll
          for (int m = 0; m < DPT + 2; ++m) {
            const float v = vbase[m * LROW + j];
            bool ok = wokj;
            if (m == 0)       ok = ok && has_lo;
            if (m == DPT + 1) ok = ok && has_hi;
            vv[j][m] = ok ? v : 0.f;
          }
        }
      }
    }

    // ---- 4. per-slot FMAs (slot s -> output row hs+r-4+s, tap row 4-s)
#pragma unroll
    for (int s = 0; s < 5; ++s) {
      if (hv && (unsigned)(r - 4 + s) < (unsigned)HSEG) {
#pragma unroll
        for (int j = 0; j < 5; ++j)
#pragma unroll
          for (int k = 0; k < DPT; ++k)
            acc[s][k] = fmaf(W[s * 15 + j],      vv[j][k],
                        fmaf(W[s * 15 + 5 + j],  vv[j][k + 1],
                        fmaf(W[s * 15 + 10 + j], vv[j][k + 2], acc[s][k])));
      }
    }

    // ---- 5. slot 0 complete -> write output row hs+r-4
    if (r >= 4) {
      const int o = hs + r - 4;
#pragma unroll
      for (int k = 0; k < DPT; ++k) {
        float* dp = dst + (((size_t)b * D_ + d0 + k) * H_ + o) * W_;
        dp[w] = acc[0][k];
      }
    }

    // ---- 6. rotate accumulator slots (static indices)
#pragma unroll
    for (int s = 0; s < 4; ++s)
#pragma unroll
      for (int k = 0; k < DPT; ++k) acc[s][k] = acc[s + 1][k];
#pragma unroll
    for (int k = 0; k < DPT; ++k) acc[4][k] = 0.f;

    __syncthreads();   // drains staged loads; swap buffers (4-wave group only)
    n ^= 1;
  }
}

extern "C" void kernel_launch(void* const* d_in, const int* in_sizes, int n_in,
                              void* d_out, int out_size, void* d_ws, size_t ws_size,
                              hipStream_t stream) {
  const float* cost = (const float*)d_in[0];
  const float* wts  = (const float*)d_in[1];
  float* out = (float*)d_out;
  float* ws  = (float*)d_ws;

  dim3 grid(W_ / WT, H_ / HSEG, B_ * 2);   // 12 x 48 x 4 = 2304 blocks
  dim3 block(WT, NTY);                     // 64 x 4 = 256 threads

  lga_pass<<<grid, block, 0, stream>>>(cost, wts, out);
  lga_pass<<<grid, block, 0, stream>>>(out, wts, ws);
  lga_pass<<<grid, block, 0, stream>>>(ws, wts, out);
}

// Round 14
// 552.410 us; speedup vs baseline: 1.3964x; 1.0007x over previous
//
#include <hip/hip_runtime.h>

// LGA3: 3 chained local-guided-aggregation passes, rolling-accumulator stencil.
// d-split independent blocks (R13) + LDS-staged weights (R11) with single-buffered
// two-barrier iterations:
//   per iter: async-stage cost row r AND weight slice r (global_load_lds)
//             -> __syncthreads (drain)  -> consume (imm-offset ds_reads + FMA)
//             -> __syncthreads (buffer protect) -> next iter overwrites.
// 29.7 KB LDS/block -> 4 independent 4-wave blocks/CU; weight addressing is
// zero-VALU (imm offsets), weight latency ~120cy LDS instead of ~900cy VMEM.
// cost [B=2, D=64, H=384, W=768] fp32, weights [B, 75, H, W] fp32.
// out[b,d,h,w] = sum_{i,j in 5x5} w0*c[d-1,h+i-2,w+j-2] + w1*c[d,..] + w2*c[d+1,..]

#define B_ 2
#define D_ 64
#define H_ 384
#define W_ 768
static constexpr int HW    = H_ * W_;
static constexpr int DPT   = 8;          // disparities per thread
static constexpr int NTY   = 4;          // 4 waves/block -> 32 d per block
static constexpr int WT    = 64;
static constexpr int HSEG  = 8;          // output rows per block
static constexpr int RITER = HSEG + 4;   // 12 streamed input rows
static constexpr int LROW  = 72;         // floats per LDS plane row (288 B)
static constexpr int LRWS  = 34;         // LDS rows: planes dbase..dbase+33
static constexpr int NGRAN = LRWS * 18;  // 612 granules of 16 B per cost stage
static constexpr int NCH_C = 10;         // 1-KiB chunks per cost stage
static constexpr int NCH_W = 19;         // 1-KiB chunks per weight stage
static constexpr int WCH   = 76;         // padded weight channels in LDS

__device__ __forceinline__ void gld_lds16(const float* g, float* l) {
  __builtin_amdgcn_global_load_lds((const __attribute__((address_space(1))) unsigned int*)g,
                                   (__attribute__((address_space(3))) unsigned int*)l,
                                   16, 0, 0);
}

__global__ __launch_bounds__(256, 1) void lga_pass(const float* __restrict__ src,
                                                   const float* __restrict__ wts,
                                                   float* __restrict__ dst) {
  __shared__ float cl[NCH_C * 256];       // 10240 B cost tile (single-buffered)
  __shared__ float wl[WCH * 64];          // 19456 B weight slice (single-buffered)

  const int tx    = threadIdx.x;          // 0..63 (lane; wave = ty)
  const int ty    = threadIdx.y;          // 0..3
  const int bx    = blockIdx.x;
  const int w0    = bx * WT, w = w0 + tx;
  const int hs    = blockIdx.y * HSEG;
  const int b     = blockIdx.z >> 1;
  const int dhalf = blockIdx.z & 1;
  const int dbase = dhalf * 32 - 1;       // plane held in LDS row 0
  const int d0    = dhalf * 32 + ty * DPT;

  const float* sb  = src + (size_t)b * D_ * HW;
  const float* wtb = wts + (size_t)b * 75 * HW;

  const bool has_lo = (d0 > 0);
  const bool has_hi = (d0 + DPT < D_);
  const bool edge   = (bx == 0) || (bx == W_ / WT - 1);

  float acc[5][DPT];
#pragma unroll
  for (int s = 0; s < 5; ++s)
#pragma unroll
    for (int k = 0; k < DPT; ++k) acc[s][k] = 0.f;

#pragma unroll 1
  for (int r = 0; r < RITER; ++r) {
    // ---- 1a. stage cost row r: LDS rows 0..33 <- planes clamp(dbase+p,0,63)
    {
      int h_in = hs - 2 + r;
      h_in = h_in < 0 ? 0 : (h_in >= H_ ? H_ - 1 : h_in);   // garbage rows hv-guarded
#pragma unroll
      for (int q = 0; q < 3; ++q) {
        const int c = ty + q * 4;                   // wave-uniform chunk id
        if (c < NCH_C) {
          int G = c * 64 + tx;                      // granule id
          G = G > NGRAN - 1 ? NGRAN - 1 : G;        // clamp tail (slack)
          const int p = G / 18;                     // LDS row
          const int k = G - p * 18;                 // granule within row
          int pd = dbase + p;                       // source plane
          pd = pd < 0 ? 0 : (pd > D_ - 1 ? D_ - 1 : pd);
          long idx = (long)pd * HW + (long)h_in * W_ + (w0 - 4) + (k << 2);
          idx = idx < 0 ? 0 : idx;
          const long mx = (long)D_ * HW - 4;
          idx = idx > mx ? mx : idx;
          gld_lds16(sb + idx, &cl[c * 256]);
        }
      }
    }
    // ---- 1b. stage weight slice r: LDS channel ch = s*15+g*5+j <-
    //          weights[b][(4-s)*5+j+25g][clamp(hs+r-4+s)][w0..w0+63]
    {
#pragma unroll
      for (int q = 0; q < 5; ++q) {
        const int ci = ty + q * 4;                  // wave-uniform chunk id
        if (ci < NCH_W) {
          int ch = ci * 4 + (tx >> 4);
          ch = ch > 74 ? 74 : ch;                   // channel 75 = dup pad, never read
          const int s  = ch / 15;
          const int t  = ch - s * 15;
          const int g  = t / 5;
          const int j  = t - g * 5;
          const int cw = (4 - s) * 5 + j + g * 25;
          int o = hs + r - 4 + s;
          o = o < 0 ? 0 : (o >= H_ ? H_ - 1 : o);   // clamped rows never consumed
          const float* p = wtb + (size_t)cw * HW + (size_t)o * W_ + w0 + ((tx & 15) << 2);
          gld_lds16(p, &wl[ci * 256]);
        }
      }
    }

    __syncthreads();   // drain: cost row + weight slice resident in LDS

    // ---- 2. LDS -> vv; masks only where needed (edge blocks / d-edge waves)
    const int  h_in = hs - 2 + r;
    const bool hv   = (unsigned)h_in < (unsigned)H_;      // wave-uniform
    float vv[5][DPT + 2];
    if (hv) {
      const float* vbase = cl + ty * DPT * LROW + tx + 2;
      if (!edge) {                                        // interior: no lane masks
#pragma unroll
        for (int j = 0; j < 5; ++j)
#pragma unroll
          for (int m = 0; m < DPT + 2; ++m)
            vv[j][m] = vbase[m * LROW + j];
        if (!has_lo) {                                    // uniform wave branch
#pragma unroll
          for (int j = 0; j < 5; ++j) vv[j][0] = 0.f;
        }
        if (!has_hi) {
#pragma unroll
          for (int j = 0; j < 5; ++j) vv[j][DPT + 1] = 0.f;
        }
      } else {
#pragma unroll
        for (int j = 0; j < 5; ++j) {
          const bool wokj = (unsigned)(w + j - 2) < (unsigned)W_;
#pragma unroll
          for (int m = 0; m < DPT + 2; ++m) {
            const float v = vbase[m * LROW + j];
            bool ok = wokj;
            if (m == 0)       ok = ok && has_lo;
            if (m == DPT + 1) ok = ok && has_hi;
            vv[j][m] = ok ? v : 0.f;
          }
        }
      }
    }

    // ---- 3. per-slot: 15 imm-offset weight ds_reads + 120 FMAs
#pragma unroll
    for (int s = 0; s < 5; ++s) {
      if (hv && (unsigned)(r - 4 + s) < (unsigned)HSEG) { // wave-uniform
        const float* wsl = wl + s * 15 * 64 + tx;
#pragma unroll
        for (int j = 0; j < 5; ++j) {
          const float w0v = wsl[(j)      * 64];
          const float w1v = wsl[(5 + j)  * 64];
          const float w2v = wsl[(10 + j) * 64];
#pragma unroll
          for (int k = 0; k < DPT; ++k)
            acc[s][k] = fmaf(w0v, vv[j][k],
                        fmaf(w1v, vv[j][k + 1],
                        fmaf(w2v, vv[j][k + 2], acc[s][k])));
        }
      }
    }

    // ---- 4. slot 0 complete -> write output row hs+r-4
    if (r >= 4) {
      const int o = hs + r - 4;
#pragma unroll
      for (int k = 0; k < DPT; ++k) {
        float* dp = dst + (((size_t)b * D_ + d0 + k) * H_ + o) * W_;
        dp[w] = acc[0][k];
      }
    }

    // ---- 5. rotate accumulator slots (static indices)
#pragma unroll
    for (int s = 0; s < 4; ++s)
#pragma unroll
      for (int k = 0; k < DPT; ++k) acc[s][k] = acc[s + 1][k];
#pragma unroll
    for (int k = 0; k < DPT; ++k) acc[4][k] = 0.f;

    __syncthreads();   // all waves done reading cl/wl before next iter's overwrite
  }
}

extern "C" void kernel_launch(void* const* d_in, const int* in_sizes, int n_in,
                              void* d_out, int out_size, void* d_ws, size_t ws_size,
                              hipStream_t stream) {
  const float* cost = (const float*)d_in[0];
  const float* wts  = (const float*)d_in[1];
  float* out = (float*)d_out;
  float* ws  = (float*)d_ws;

  dim3 grid(W_ / WT, H_ / HSEG, B_ * 2);   // 12 x 48 x 4 = 2304 blocks
  dim3 block(WT, NTY);                     // 64 x 4 = 256 threads

  lga_pass<<<grid, block, 0, stream>>>(cost, wts, out);
  lga_pass<<<grid, block, 0, stream>>>(out, wts, ws);
  lga_pass<<<grid, block, 0, stream>>>(ws, wts, out);
}